// Round 1
// 1287.333 us; speedup vs baseline: 1.2539x; 1.2539x over previous
//
#include <hip/hip_runtime.h>

// ---------------- problem constants ----------------
constexpr int NP        = 1000000;     // number of gaussians
constexpr int FC        = 64;          // feature channels
constexpr int SC        = 16;          // semantic channels
constexpr int SCALE_XYZ = 8388608;     // 512*512*32
constexpr int SCALE_YZ  = 16384;       // 512*32
constexpr int SCALE_Z   = 32;
constexpr int CODE_SPACE = 4 * SCALE_XYZ;        // 33,554,432
constexpr int NWORDS     = CODE_SPACE / 32;      // 1,048,576
constexpr int WORDS_PER_BLOCK = 1024;
constexpr int NBLK       = NWORDS / WORDS_PER_BLOCK; // 1024
constexpr int NSCAN      = (NP + 1023) / 1024;       // 977 blocks for counts-scan

// output layout (element offsets into float* d_out)
constexpr int OFF_MU   = 0;
constexpr int OFF_SCL  = 3 * NP;
constexpr int OFF_ROT  = 6 * NP;
constexpr int OFF_FEAT = 10 * NP;
constexpr int OFF_SEM  = 74 * NP;
constexpr int OFF_VOX  = 90 * NP;

// ---------------- kernels ----------------

// per-point voxel code; set presence bit in dense mask
__global__ void k_code(const float* __restrict__ mu, const int* __restrict__ batch,
                       unsigned* __restrict__ mask, int* __restrict__ codes) {
    int i = blockIdx.x * blockDim.x + threadIdx.x;
    if (i >= NP) return;
    float x = mu[i * 3 + 0], y = mu[i * 3 + 1], z = mu[i * 3 + 2];
    // must match XLA bit-exactly: (mu - pc_min) / vox, IEEE fp32 division, floor, int cast
    int ix = (int)floorf((x - (-51.2f)) / 0.2f);
    int iy = (int)floorf((y - (-51.2f)) / 0.2f);
    int iz = (int)floorf((z - (-3.2f)) / 0.2f);
    int code = batch[i] * SCALE_XYZ + iz * SCALE_YZ + iy * SCALE_Z + ix;
    codes[i] = code;
    atomicOr(&mask[(unsigned)code >> 5], 1u << (code & 31));
}

// per-block popcount reduce (1024 words / block)
__global__ void k_reduce(const unsigned* __restrict__ mask, unsigned* __restrict__ blockSums) {
    __shared__ unsigned sh[256];
    int t = threadIdx.x;
    int base = blockIdx.x * WORDS_PER_BLOCK + t * 4;
    unsigned s = 0;
    for (int k = 0; k < 4; k++) s += __popc(mask[base + k]);
    sh[t] = s;
    __syncthreads();
    for (int off = 128; off > 0; off >>= 1) {
        if (t < off) sh[t] += sh[t + off];
        __syncthreads();
    }
    if (t == 0) blockSums[blockIdx.x] = sh[0];
}

// scan 1024 block sums -> exclusive offsets; write total group count M
__global__ void k_scan_blocks(unsigned* __restrict__ blockSums, unsigned* __restrict__ dM) {
    __shared__ unsigned sh[NBLK];
    int t = threadIdx.x;
    unsigned v = blockSums[t];
    sh[t] = v;
    __syncthreads();
    for (int off = 1; off < NBLK; off <<= 1) {
        unsigned add = (t >= off) ? sh[t - off] : 0u;
        __syncthreads();
        sh[t] += add;
        __syncthreads();
    }
    blockSums[t] = sh[t] - v;   // exclusive
    if (t == NBLK - 1) *dM = sh[t];
}

// per-word exclusive popcount offsets
__global__ void k_word_off(const unsigned* __restrict__ mask, const unsigned* __restrict__ blockOff,
                           unsigned* __restrict__ wordOff) {
    __shared__ unsigned sh[256];
    int t = threadIdx.x;
    int base = blockIdx.x * WORDS_PER_BLOCK + t * 4;
    unsigned p[4], s = 0;
    for (int k = 0; k < 4; k++) { p[k] = __popc(mask[base + k]); s += p[k]; }
    sh[t] = s;
    __syncthreads();
    unsigned v = s;
    for (int off = 1; off < 256; off <<= 1) {
        unsigned add = (t >= off) ? sh[t - off] : 0u;
        __syncthreads();
        sh[t] += add;
        __syncthreads();
    }
    unsigned myOff = blockOff[blockIdx.x] + sh[t] - v;   // exclusive for this thread's 4 words
    for (int k = 0; k < 4; k++) { wordOff[base + k] = myOff; myOff += p[k]; }
}

// scatter sorted unique codes: ucode[rank] = code
__global__ void k_scatter(const unsigned* __restrict__ mask, const unsigned* __restrict__ wordOff,
                          int* __restrict__ ucode) {
    int w = blockIdx.x * blockDim.x + threadIdx.x;
    if (w >= NWORDS) return;
    unsigned bits = mask[w];
    unsigned r = wordOff[w];
    int base = w * 32;
    while (bits) {
        int b = __ffs(bits) - 1;
        bits &= bits - 1;
        ucode[r++] = base + b;
    }
}

// per-point: rank + intra-group slot (single 4B atomic per point)
__global__ void k_rank(const int* __restrict__ codes, const unsigned* __restrict__ mask,
                       const unsigned* __restrict__ wordOff, int* __restrict__ rank,
                       unsigned* __restrict__ intra, unsigned* __restrict__ counts) {
    int i = blockIdx.x * blockDim.x + threadIdx.x;
    if (i >= NP) return;
    int code = codes[i];
    unsigned w = (unsigned)code >> 5;
    unsigned r = wordOff[w] + __popc(mask[w] & ((1u << (code & 31)) - 1u));
    rank[i] = (int)r;
    intra[i] = atomicAdd(&counts[r], 1u);
}

// ---- exclusive scan of counts[NP] -> segStart[NP] (3-stage) ----
__global__ void k_creduce(const unsigned* __restrict__ counts, unsigned* __restrict__ csums) {
    __shared__ unsigned sh[256];
    int t = threadIdx.x;
    int base = blockIdx.x * 1024 + t * 4;
    unsigned s = 0;
    for (int k = 0; k < 4; k++) { int e = base + k; if (e < NP) s += counts[e]; }
    sh[t] = s;
    __syncthreads();
    for (int off = 128; off > 0; off >>= 1) {
        if (t < off) sh[t] += sh[t + off];
        __syncthreads();
    }
    if (t == 0) csums[blockIdx.x] = sh[0];
}

__global__ void k_cscan(unsigned* __restrict__ csums) {
    __shared__ unsigned sh[1024];
    int t = threadIdx.x;
    unsigned v = (t < NSCAN) ? csums[t] : 0u;
    sh[t] = v;
    __syncthreads();
    for (int off = 1; off < 1024; off <<= 1) {
        unsigned add = (t >= off) ? sh[t - off] : 0u;
        __syncthreads();
        sh[t] += add;
        __syncthreads();
    }
    if (t < NSCAN) csums[t] = sh[t] - v;   // exclusive
}

__global__ void k_coff(const unsigned* __restrict__ counts, const unsigned* __restrict__ csums,
                       unsigned* __restrict__ segStart) {
    __shared__ unsigned sh[256];
    int t = threadIdx.x;
    int base = blockIdx.x * 1024 + t * 4;
    unsigned p[4], s = 0;
    for (int k = 0; k < 4; k++) { int e = base + k; p[k] = (e < NP) ? counts[e] : 0u; s += p[k]; }
    sh[t] = s;
    __syncthreads();
    unsigned v = s;
    for (int off = 1; off < 256; off <<= 1) {
        unsigned add = (t >= off) ? sh[t - off] : 0u;
        __syncthreads();
        sh[t] += add;
        __syncthreads();
    }
    unsigned myOff = csums[blockIdx.x] + sh[t] - v;
    for (int k = 0; k < 4; k++) { int e = base + k; if (e < NP) segStart[e] = myOff; myOff += p[k]; }
}

// counting-sort scatter: order[segStart[rank] + intra] = point index
__global__ void k_order(const int* __restrict__ rank, const unsigned* __restrict__ intra,
                        const unsigned* __restrict__ segStart, int* __restrict__ order) {
    int i = blockIdx.x * blockDim.x + threadIdx.x;
    if (i >= NP) return;
    order[segStart[rank[i]] + intra[i]] = i;
}

// fused gather: one wave64 per group. Computes means (mu/scl/feat/sem),
// antipodal quaternion mean + normalize, voxel decode. Writes ALL 94*NP
// output floats exactly once (no memset, no atomics, no div passes).
__global__ __launch_bounds__(256) void k_gather(
        const float* __restrict__ mu, const float* __restrict__ scl,
        const float* __restrict__ rot, const float* __restrict__ feat,
        const float* __restrict__ sem, const unsigned* __restrict__ counts,
        const unsigned* __restrict__ segStart, const int* __restrict__ order,
        const int* __restrict__ ucode, const unsigned* __restrict__ dM,
        float* __restrict__ out) {
    int wid  = (int)((blockIdx.x * blockDim.x + threadIdx.x) >> 6);
    int lane = (int)(threadIdx.x & 63);
    if (wid >= NP) return;
    int r = wid;
    int M = (int)(*dM);

    float facc = 0.f, sacc = 0.f, xacc = 0.f, racc = 0.f;
    int cnt = 0;
    bool rotlane = (lane >= 8 && lane < 12);

    if (r < M) {                       // wave-uniform branch (r, M uniform per wave)
        cnt = (int)counts[r];
        int start = (int)segStart[r];

        // ref point = min original index in group (matches segment_min(arange))
        unsigned refp = 0xFFFFFFFFu;
        for (int j = lane; j < cnt; j += 64)
            refp = min(refp, (unsigned)order[start + j]);
        for (int off = 32; off > 0; off >>= 1) {
            unsigned o = (unsigned)__shfl_xor((int)refp, off, 64);
            refp = min(refp, o);
        }

        const float4* rot4 = (const float4*)rot;
        float4 qr4 = make_float4(0.f, 0.f, 0.f, 0.f);
        if (rotlane) qr4 = rot4[refp];

        for (int j = 0; j < cnt; ++j) {
            int pj = order[start + j];                 // wave-uniform
            facc += feat[pj * 64 + lane];              // coalesced 256B/point
            if (lane < 16) sacc += sem[pj * 16 + lane];
            if (lane < 3)  xacc += mu[pj * 3 + lane];
            else if (lane >= 4 && lane < 7) xacc += scl[pj * 3 + (lane - 4)];
            else if (rotlane) {
                float4 q4 = rot4[pj];
                float d = q4.x * qr4.x + q4.y * qr4.y + q4.z * qr4.z + q4.w * qr4.w + 1e-8f;
                float s = (d > 0.f) ? 1.f : ((d < 0.f) ? -1.f : 0.f);
                float comp = (lane == 8) ? q4.x : (lane == 9) ? q4.y
                           : (lane == 10) ? q4.z : q4.w;
                racc += comp * s;
            }
        }
    }

    float cntf = (float)(cnt > 0 ? cnt : 1);           // denom = max(count,1)

    out[OFF_FEAT + r * 64 + lane] = facc / cntf;
    if (lane < 16) out[OFF_SEM + r * 16 + lane] = sacc / cntf;

    if (lane < 3) {
        out[OFF_MU + r * 3 + lane] = xacc / cntf;
    } else if (lane >= 4 && lane < 7) {
        out[OFF_SCL + r * 3 + (lane - 4)] = xacc / cntf;
    } else if (rotlane) {
        float p = racc / cntf;
        float nsq = p * p;
        nsq += __shfl_xor(nsq, 1, 64);                 // lanes 8..11 aligned 4-group
        nsq += __shfl_xor(nsq, 2, 64);
        float n = fmaxf(sqrtf(nsq), 1e-12f);
        out[OFF_ROT + r * 4 + (lane - 8)] = p / n;
    } else if (lane == 16) {
        float4 v;
        if (r < M) {
            int c = ucode[r];
            int vb = c >> 23;                          // / 8388608 (c >= 0)
            int rem = c & (SCALE_XYZ - 1);
            int vz = rem >> 14;                        // / 16384
            rem &= (SCALE_YZ - 1);
            int vy = rem >> 5;                         // / 32
            int vx = rem & 31;
            v = make_float4((float)vb, (float)vz, (float)vy, (float)vx);
        } else {
            // jnp floor-div/mod semantics on unq = -1
            v = make_float4(-1.f, 511.f, 511.f, 31.f);
        }
        ((float4*)(out + OFF_VOX))[r] = v;
    }
}

// ---------------- launcher ----------------
extern "C" void kernel_launch(void* const* d_in, const int* in_sizes, int n_in,
                              void* d_out, int out_size, void* d_ws, size_t ws_size,
                              hipStream_t stream) {
    const float* mu   = (const float*)d_in[0];
    const float* scl  = (const float*)d_in[1];
    const float* rot  = (const float*)d_in[2];
    const float* feat = (const float*)d_in[3];
    const float* sem  = (const float*)d_in[4];
    const int*   bidx = (const int*)d_in[5];
    float* out = (float*)d_out;

    // workspace layout (28.45 MB total, same footprint as previous version)
    char* w = (char*)d_ws;
    unsigned* mask      = (unsigned*)(w);                        // 4 MB
    unsigned* wordOff   = (unsigned*)(w + (4u << 20));           // 4 MB
    unsigned* blockSums = (unsigned*)(w + (8u << 20));           // 4 KB
    unsigned* cblock    = (unsigned*)(w + (8u << 20) + 8192);    // 4 KB (counts-scan sums)
    unsigned* dM        = (unsigned*)(w + (8u << 20) + 16384);   // 4 B
    char* w2 = w + (8u << 20) + 65536;
    int*      codes  = (int*)(w2);                               // 4 MB
    int*      rank   = (int*)(w2 + 4000000u);                    // 4 MB
    unsigned* intra  = (unsigned*)(w2 + 8000000u);               // 4 MB
    unsigned* counts = (unsigned*)(w2 + 12000000u);              // 4 MB
    int*      ucode  = (int*)(w2 + 16000000u);                   // 4 MB
    // aliases (dead buffers reused):
    unsigned* segStart = wordOff;   // wordOff dead after k_rank
    int*      order    = codes;     // codes dead after k_rank

    // NOTE: no memset of d_out — k_gather writes every output element.
    hipMemsetAsync(mask, 0, (size_t)NWORDS * 4, stream);
    hipMemsetAsync(counts, 0, (size_t)NP * 4, stream);

    const int B = 256;
    int gN = (NP + B - 1) / B;

    k_code<<<gN, B, 0, stream>>>(mu, bidx, mask, codes);
    k_reduce<<<NBLK, B, 0, stream>>>(mask, blockSums);
    k_scan_blocks<<<1, NBLK, 0, stream>>>(blockSums, dM);
    k_word_off<<<NBLK, B, 0, stream>>>(mask, blockSums, wordOff);
    k_scatter<<<NWORDS / B, B, 0, stream>>>(mask, wordOff, ucode);
    k_rank<<<gN, B, 0, stream>>>(codes, mask, wordOff, rank, intra, counts);
    k_creduce<<<NSCAN, B, 0, stream>>>(counts, cblock);
    k_cscan<<<1, 1024, 0, stream>>>(cblock);
    k_coff<<<NSCAN, B, 0, stream>>>(counts, cblock, segStart);   // overwrites wordOff (dead)
    k_order<<<gN, B, 0, stream>>>(rank, intra, segStart, order); // overwrites codes (dead)
    k_gather<<<(NP + 3) / 4, B, 0, stream>>>(mu, scl, rot, feat, sem,
                                             counts, segStart, order, ucode, dM, out);
}

// Round 2
// 956.753 us; speedup vs baseline: 1.6872x; 1.3455x over previous
//
#include <hip/hip_runtime.h>

// ---------------- problem constants ----------------
constexpr int NP        = 1000000;     // number of gaussians
constexpr int FC        = 64;          // feature channels
constexpr int SC        = 16;          // semantic channels
constexpr int SCALE_XYZ = 8388608;     // 512*512*32
constexpr int SCALE_YZ  = 16384;       // 512*32
constexpr int SCALE_Z   = 32;
constexpr int CODE_SPACE = 4 * SCALE_XYZ;        // 33,554,432
constexpr int NWORDS     = CODE_SPACE / 32;      // 1,048,576
constexpr int WORDS_PER_BLOCK = 1024;
constexpr int NBLK       = NWORDS / WORDS_PER_BLOCK; // 1024
constexpr int NSCAN      = (NP + 1023) / 1024;       // 977 blocks for counts-scan

// output layout (element offsets into float* d_out)
constexpr int OFF_MU   = 0;
constexpr int OFF_SCL  = 3 * NP;
constexpr int OFF_ROT  = 6 * NP;
constexpr int OFF_FEAT = 10 * NP;
constexpr int OFF_SEM  = 74 * NP;
constexpr int OFF_VOX  = 90 * NP;

// ---------------- kernels ----------------

// per-point voxel code; set presence bit in dense mask
__global__ void k_code(const float* __restrict__ mu, const int* __restrict__ batch,
                       unsigned* __restrict__ mask, int* __restrict__ codes) {
    int i = blockIdx.x * blockDim.x + threadIdx.x;
    if (i >= NP) return;
    float x = mu[i * 3 + 0], y = mu[i * 3 + 1], z = mu[i * 3 + 2];
    // must match XLA bit-exactly: (mu - pc_min) / vox, IEEE fp32 division, floor, int cast
    int ix = (int)floorf((x - (-51.2f)) / 0.2f);
    int iy = (int)floorf((y - (-51.2f)) / 0.2f);
    int iz = (int)floorf((z - (-3.2f)) / 0.2f);
    int code = batch[i] * SCALE_XYZ + iz * SCALE_YZ + iy * SCALE_Z + ix;
    codes[i] = code;
    atomicOr(&mask[(unsigned)code >> 5], 1u << (code & 31));
}

// per-block popcount reduce (1024 words / block)
__global__ void k_reduce(const unsigned* __restrict__ mask, unsigned* __restrict__ blockSums) {
    __shared__ unsigned sh[256];
    int t = threadIdx.x;
    int base = blockIdx.x * WORDS_PER_BLOCK + t * 4;
    unsigned s = 0;
    for (int k = 0; k < 4; k++) s += __popc(mask[base + k]);
    sh[t] = s;
    __syncthreads();
    for (int off = 128; off > 0; off >>= 1) {
        if (t < off) sh[t] += sh[t + off];
        __syncthreads();
    }
    if (t == 0) blockSums[blockIdx.x] = sh[0];
}

// scan 1024 block sums -> exclusive offsets; write total group count M
__global__ void k_scan_blocks(unsigned* __restrict__ blockSums, unsigned* __restrict__ dM) {
    __shared__ unsigned sh[NBLK];
    int t = threadIdx.x;
    unsigned v = blockSums[t];
    sh[t] = v;
    __syncthreads();
    for (int off = 1; off < NBLK; off <<= 1) {
        unsigned add = (t >= off) ? sh[t - off] : 0u;
        __syncthreads();
        sh[t] += add;
        __syncthreads();
    }
    blockSums[t] = sh[t] - v;   // exclusive
    if (t == NBLK - 1) *dM = sh[t];
}

// per-word exclusive popcount offsets
__global__ void k_word_off(const unsigned* __restrict__ mask, const unsigned* __restrict__ blockOff,
                           unsigned* __restrict__ wordOff) {
    __shared__ unsigned sh[256];
    int t = threadIdx.x;
    int base = blockIdx.x * WORDS_PER_BLOCK + t * 4;
    unsigned p[4], s = 0;
    for (int k = 0; k < 4; k++) { p[k] = __popc(mask[base + k]); s += p[k]; }
    sh[t] = s;
    __syncthreads();
    unsigned v = s;
    for (int off = 1; off < 256; off <<= 1) {
        unsigned add = (t >= off) ? sh[t - off] : 0u;
        __syncthreads();
        sh[t] += add;
        __syncthreads();
    }
    unsigned myOff = blockOff[blockIdx.x] + sh[t] - v;   // exclusive for this thread's 4 words
    for (int k = 0; k < 4; k++) { wordOff[base + k] = myOff; myOff += p[k]; }
}

// scatter sorted unique codes: ucode[rank] = code
__global__ void k_scatter(const unsigned* __restrict__ mask, const unsigned* __restrict__ wordOff,
                          int* __restrict__ ucode) {
    int w = blockIdx.x * blockDim.x + threadIdx.x;
    if (w >= NWORDS) return;
    unsigned bits = mask[w];
    unsigned r = wordOff[w];
    int base = w * 32;
    while (bits) {
        int b = __ffs(bits) - 1;
        bits &= bits - 1;
        ucode[r++] = base + b;
    }
}

// per-point: rank + intra-group slot (single 4B atomic per point)
__global__ void k_rank(const int* __restrict__ codes, const unsigned* __restrict__ mask,
                       const unsigned* __restrict__ wordOff, int* __restrict__ rank,
                       unsigned* __restrict__ intra, unsigned* __restrict__ counts) {
    int i = blockIdx.x * blockDim.x + threadIdx.x;
    if (i >= NP) return;
    int code = codes[i];
    unsigned w = (unsigned)code >> 5;
    unsigned r = wordOff[w] + __popc(mask[w] & ((1u << (code & 31)) - 1u));
    rank[i] = (int)r;
    intra[i] = atomicAdd(&counts[r], 1u);
}

// ---- exclusive scan of counts[NP] -> seg[NP] = {start, count} (3-stage) ----
__global__ void k_creduce(const unsigned* __restrict__ counts, unsigned* __restrict__ csums) {
    __shared__ unsigned sh[256];
    int t = threadIdx.x;
    int base = blockIdx.x * 1024 + t * 4;
    unsigned s = 0;
    for (int k = 0; k < 4; k++) { int e = base + k; if (e < NP) s += counts[e]; }
    sh[t] = s;
    __syncthreads();
    for (int off = 128; off > 0; off >>= 1) {
        if (t < off) sh[t] += sh[t + off];
        __syncthreads();
    }
    if (t == 0) csums[blockIdx.x] = sh[0];
}

__global__ void k_cscan(unsigned* __restrict__ csums) {
    __shared__ unsigned sh[1024];
    int t = threadIdx.x;
    unsigned v = (t < NSCAN) ? csums[t] : 0u;
    sh[t] = v;
    __syncthreads();
    for (int off = 1; off < 1024; off <<= 1) {
        unsigned add = (t >= off) ? sh[t - off] : 0u;
        __syncthreads();
        sh[t] += add;
        __syncthreads();
    }
    if (t < NSCAN) csums[t] = sh[t] - v;   // exclusive
}

// writes packed seg[e] = {segStart, count}
__global__ void k_coff(const unsigned* __restrict__ counts, const unsigned* __restrict__ csums,
                       uint2* __restrict__ seg) {
    __shared__ unsigned sh[256];
    int t = threadIdx.x;
    int base = blockIdx.x * 1024 + t * 4;
    unsigned p[4], s = 0;
    for (int k = 0; k < 4; k++) { int e = base + k; p[k] = (e < NP) ? counts[e] : 0u; s += p[k]; }
    sh[t] = s;
    __syncthreads();
    unsigned v = s;
    for (int off = 1; off < 256; off <<= 1) {
        unsigned add = (t >= off) ? sh[t - off] : 0u;
        __syncthreads();
        sh[t] += add;
        __syncthreads();
    }
    unsigned myOff = csums[blockIdx.x] + sh[t] - v;
    for (int k = 0; k < 4; k++) {
        int e = base + k;
        if (e < NP) seg[e] = make_uint2(myOff, p[k]);
        myOff += p[k];
    }
}

// counting-sort scatter: order[seg[rank].start + intra] = point index
__global__ void k_order(const int* __restrict__ rank, const unsigned* __restrict__ intra,
                        const uint2* __restrict__ seg, int* __restrict__ order) {
    int i = blockIdx.x * blockDim.x + threadIdx.x;
    if (i >= NP) return;
    order[seg[rank[i]].x + intra[i]] = i;
}

// fused gather: 4 groups per wave, 16 lanes per group (sub = lane & 15).
// Each sub-lane: float4 of feat (4*sub..4*sub+3) + one extra duty:
//   sub<4: sem float4 | sub==4: mu | sub==5: scl | sub==6: rot | sub==7: vox
// Singleton groups (~98.5%) take a fast path: no reduce, no align math, rcp=1 (exact).
// Writes all 94*NP output floats exactly once (no memset, no atomics).
__global__ __launch_bounds__(256) void k_gather(
        const float* __restrict__ mu, const float* __restrict__ scl,
        const float* __restrict__ rot, const float* __restrict__ feat,
        const float* __restrict__ sem, const uint2* __restrict__ seg,
        const int* __restrict__ order, const int* __restrict__ ucode,
        float* __restrict__ out) {
    int tid = blockIdx.x * blockDim.x + threadIdx.x;
    int r   = tid >> 4;                 // group index
    int sub = tid & 15;
    if (r >= NP) return;

    uint2 ss = seg[r];
    int start = (int)ss.x;
    int cnt   = (int)ss.y;

    const float4* feat4 = (const float4*)feat;
    const float4* sem4  = (const float4*)sem;
    const float4* rot4  = (const float4*)rot;

    float4 fa = make_float4(0.f, 0.f, 0.f, 0.f);   // feat accumulator (all lanes)
    float4 ea = make_float4(0.f, 0.f, 0.f, 0.f);   // extra-duty accumulator
    float rcp = 1.f;

    if (cnt == 1) {
        int p0 = order[start];
        fa = feat4[p0 * 16 + sub];
        if (sub < 4)       ea = sem4[p0 * 4 + sub];
        else if (sub == 4) { ea.x = mu[p0*3+0];  ea.y = mu[p0*3+1];  ea.z = mu[p0*3+2]; }
        else if (sub == 5) { ea.x = scl[p0*3+0]; ea.y = scl[p0*3+1]; ea.z = scl[p0*3+2]; }
        else if (sub == 6) ea = rot4[p0];
        // sign(|q|^2 + 1e-8) == +1 for a singleton, so aligned == q; rcp stays exactly 1.
    } else if (cnt > 1) {
        rcp = 1.0f / (float)cnt;
        // ref point = min original index in group (matches segment_min(arange))
        unsigned refp = 0xFFFFFFFFu;
        for (int j = sub; j < cnt; j += 16)
            refp = min(refp, (unsigned)order[start + j]);
        refp = min(refp, (unsigned)__shfl_xor((int)refp, 8, 64));
        refp = min(refp, (unsigned)__shfl_xor((int)refp, 4, 64));
        refp = min(refp, (unsigned)__shfl_xor((int)refp, 2, 64));
        refp = min(refp, (unsigned)__shfl_xor((int)refp, 1, 64));
        float4 qr = make_float4(0.f, 0.f, 0.f, 0.f);
        if (sub == 6) qr = rot4[refp];
        for (int j = 0; j < cnt; ++j) {
            int pj = order[start + j];                 // uniform within lane-group
            float4 f = feat4[pj * 16 + sub];
            fa.x += f.x; fa.y += f.y; fa.z += f.z; fa.w += f.w;
            if (sub < 4) {
                float4 s4 = sem4[pj * 4 + sub];
                ea.x += s4.x; ea.y += s4.y; ea.z += s4.z; ea.w += s4.w;
            } else if (sub == 4) {
                ea.x += mu[pj*3+0]; ea.y += mu[pj*3+1]; ea.z += mu[pj*3+2];
            } else if (sub == 5) {
                ea.x += scl[pj*3+0]; ea.y += scl[pj*3+1]; ea.z += scl[pj*3+2];
            } else if (sub == 6) {
                float4 q = rot4[pj];
                float d = q.x*qr.x + q.y*qr.y + q.z*qr.z + q.w*qr.w + 1e-8f;
                float s = (d > 0.f) ? 1.f : ((d < 0.f) ? -1.f : 0.f);
                ea.x += q.x*s; ea.y += q.y*s; ea.z += q.z*s; ea.w += q.w*s;
            }
        }
    }
    // cnt == 0 (padded rows r >= M): accumulators stay 0, rcp = 1 -> zeros written.

    ((float4*)(out + OFF_FEAT))[r * 16 + sub] =
        make_float4(fa.x*rcp, fa.y*rcp, fa.z*rcp, fa.w*rcp);
    if (sub < 4) {
        ((float4*)(out + OFF_SEM))[r * 4 + sub] =
            make_float4(ea.x*rcp, ea.y*rcp, ea.z*rcp, ea.w*rcp);
    } else if (sub == 4) {
        out[OFF_MU + r*3 + 0] = ea.x*rcp;
        out[OFF_MU + r*3 + 1] = ea.y*rcp;
        out[OFF_MU + r*3 + 2] = ea.z*rcp;
    } else if (sub == 5) {
        out[OFF_SCL + r*3 + 0] = ea.x*rcp;
        out[OFF_SCL + r*3 + 1] = ea.y*rcp;
        out[OFF_SCL + r*3 + 2] = ea.z*rcp;
    } else if (sub == 6) {
        float px = ea.x*rcp, py = ea.y*rcp, pz = ea.z*rcp, pw = ea.w*rcp;
        float n = fmaxf(sqrtf(px*px + py*py + pz*pz + pw*pw), 1e-12f);
        ((float4*)(out + OFF_ROT))[r] = make_float4(px/n, py/n, pz/n, pw/n);
    } else if (sub == 7) {
        // ucode pre-filled with -1: decodes to (-1,511,511,31) exactly (jnp floor-div/mod on -1)
        int c = ucode[r];
        int vb = c >> 23;                 // floor-div 8388608 (works for -1 too)
        int rem = c & (SCALE_XYZ - 1);
        int vz = rem >> 14;
        rem &= (SCALE_YZ - 1);
        int vy = rem >> 5;
        int vx = rem & 31;
        ((float4*)(out + OFF_VOX))[r] = make_float4((float)vb, (float)vz, (float)vy, (float)vx);
    }
}

// ---------------- launcher ----------------
extern "C" void kernel_launch(void* const* d_in, const int* in_sizes, int n_in,
                              void* d_out, int out_size, void* d_ws, size_t ws_size,
                              hipStream_t stream) {
    const float* mu   = (const float*)d_in[0];
    const float* scl  = (const float*)d_in[1];
    const float* rot  = (const float*)d_in[2];
    const float* feat = (const float*)d_in[3];
    const float* sem  = (const float*)d_in[4];
    const int*   bidx = (const int*)d_in[5];
    float* out = (float*)d_out;

    // workspace layout (28.45 MB total, unchanged footprint)
    char* w = (char*)d_ws;
    unsigned* mask      = (unsigned*)(w);                        // 4 MB
    unsigned* wordOff   = (unsigned*)(w + (4u << 20));           // 4 MB
    unsigned* blockSums = (unsigned*)(w + (8u << 20));           // 4 KB
    unsigned* cblock    = (unsigned*)(w + (8u << 20) + 8192);    // 4 KB (counts-scan sums)
    unsigned* dM        = (unsigned*)(w + (8u << 20) + 16384);   // 4 B
    char* w2 = w + (8u << 20) + 65536;
    int*      codes  = (int*)(w2);                               // 4 MB
    int*      rank   = (int*)(w2 + 4000000u);                    // 4 MB
    unsigned* intra  = (unsigned*)(w2 + 8000000u);               // 4 MB
    unsigned* counts = (unsigned*)(w2 + 12000000u);              // 4 MB
    int*      ucode  = (int*)(w2 + 16000000u);                   // 4 MB
    // aliases (dead buffers reused):
    uint2* seg   = (uint2*)w;     // over mask+wordOff (8 MB, dead after k_rank)
    int*   order = codes;         // codes dead after k_rank

    // NOTE: no memset of d_out — k_gather writes every output element.
    hipMemsetAsync(mask, 0, (size_t)NWORDS * 4, stream);
    hipMemsetAsync(counts, 0, (size_t)NP * 4, stream);
    hipMemsetAsync(ucode, 0xFF, (size_t)NP * 4, stream);   // -1 => padded vox pattern

    const int B = 256;
    int gN = (NP + B - 1) / B;

    k_code<<<gN, B, 0, stream>>>(mu, bidx, mask, codes);
    k_reduce<<<NBLK, B, 0, stream>>>(mask, blockSums);
    k_scan_blocks<<<1, NBLK, 0, stream>>>(blockSums, dM);
    k_word_off<<<NBLK, B, 0, stream>>>(mask, blockSums, wordOff);
    k_scatter<<<NWORDS / B, B, 0, stream>>>(mask, wordOff, ucode);
    k_rank<<<gN, B, 0, stream>>>(codes, mask, wordOff, rank, intra, counts);
    k_creduce<<<NSCAN, B, 0, stream>>>(counts, cblock);
    k_cscan<<<1, 1024, 0, stream>>>(cblock);
    k_coff<<<NSCAN, B, 0, stream>>>(counts, cblock, seg);        // overwrites mask+wordOff (dead)
    k_order<<<gN, B, 0, stream>>>(rank, intra, seg, order);      // overwrites codes (dead)
    k_gather<<<NP * 16 / B, B, 0, stream>>>(mu, scl, rot, feat, sem,
                                            seg, order, ucode, out);
}